// Round 5
// baseline (1987.148 us; speedup 1.0000x reference)
//
#include <hip/hip_runtime.h>

#define HID   2048
#define S_LEN 2048
#define NBATCH 2
#define ROWS  (NBATCH*S_LEN)      // 4096
#define INTER 4096
#define GN    1024
#define NPROJ (2*INTER+2*GN)      // 10240
#define CONVD 6144
#define NH    64
#define HD    64
#define NST   128

typedef __attribute__((ext_vector_type(8))) short bf16x8;
typedef __attribute__((ext_vector_type(4))) float f32x4;

__device__ __forceinline__ unsigned short f2b(float f) {
  union { float f; unsigned u; } a; a.f = f;
  unsigned u = a.u;
  unsigned r = (u + 0x7fffu + ((u >> 16) & 1u)) >> 16;
  return (unsigned short)r;
}

__device__ __forceinline__ float b2f(unsigned short u) {
  union { unsigned u; float f; } a; a.u = ((unsigned)u) << 16; return a.f;
}

__device__ __forceinline__ void unpack2(unsigned u, float& lo, float& hi) {
  union { unsigned u; float f; } a, b;
  a.u = u << 16; b.u = u & 0xffff0000u;
  lo = a.f; hi = b.f;
}

__device__ __forceinline__ void gload16(const void* g, void* l) {
  __builtin_amdgcn_global_load_lds(
      (const __attribute__((address_space(1))) void*)g,
      (__attribute__((address_space(3))) void*)l, 16, 0, 0);
}

// ---------------- elementwise cast f32 -> bf16 (row-major kept) --------------
__global__ __launch_bounds__(256) void cast_k(const float* __restrict__ src,
                                              unsigned short* __restrict__ dst) {
  int i = blockIdx.x * 256 + threadIdx.x;
  float4 v = ((const float4*)src)[i];
  ushort4 o;
  o.x = f2b(v.x); o.y = f2b(v.y); o.z = f2b(v.z); o.w = f2b(v.w);
  ((ushort4*)dst)[i] = o;
}

// ---------------- transpose-cast: src f32 [R][Cc] -> dst bf16 [Cc][R] --------
__global__ __launch_bounds__(256) void tcast_k(const float* __restrict__ src,
                                               unsigned short* __restrict__ dst,
                                               int R, int Cc) {
  __shared__ unsigned short tile[64][65];
  int c0 = blockIdx.x * 64, r0 = blockIdx.y * 64;
  int tid = threadIdx.x;
  int tr = tid >> 4, tc = (tid & 15) * 4;
#pragma unroll
  for (int i = 0; i < 4; i++) {
    int r = tr + i * 16;
    float4 v = *(const float4*)(src + (size_t)(r0 + r) * Cc + c0 + tc);
    tile[r][tc + 0] = f2b(v.x); tile[r][tc + 1] = f2b(v.y);
    tile[r][tc + 2] = f2b(v.z); tile[r][tc + 3] = f2b(v.w);
  }
  __syncthreads();
#pragma unroll
  for (int i = 0; i < 4; i++) {
    int cc = tr + i * 16;
    ushort4 o;
    o.x = tile[tc + 0][cc]; o.y = tile[tc + 1][cc];
    o.z = tile[tc + 2][cc]; o.w = tile[tc + 3][cc];
    *(ushort4*)(dst + (size_t)(c0 + cc) * R + r0 + tc) = o;
  }
}

// ---------------- bf16 GEMM: C[M,N] = A[M,K] * Bt[N,K]^T ---------------------
// 128x128 tile, BK=32, 256 thr (2x2 waves of 64x64), global_load_lds w=16,
// involution XOR-swizzle (src granule pre-swizzled, linear LDS, swizzled read).
template <typename OutT>
__global__ __launch_bounds__(256) void gemm_bt(const unsigned short* __restrict__ A,
                                               const unsigned short* __restrict__ Bt,
                                               OutT* __restrict__ C,
                                               int M, int N, int K) {
  __shared__ unsigned short lsA[128 * 32];
  __shared__ unsigned short lsB[128 * 32];
  const int tid = threadIdx.x;
  const int w = tid >> 6, lane = tid & 63;
  const int m0 = blockIdx.y * 128, n0 = blockIdx.x * 128;
  const int wr = w >> 1, wc = w & 1;
  const int l16 = lane & 15, kq = lane >> 4;

  const int rr = tid >> 2;
  const int gl = tid & 3;
  const int gsw = ((gl ^ (rr & 3)) * 8);              // swizzled src granule (elems)
  const unsigned short* Ar0 = A + (size_t)(m0 + rr) * K + gsw;
  const unsigned short* Ar1 = A + (size_t)(m0 + rr + 64) * K + gsw;
  const unsigned short* Br0 = Bt + (size_t)(n0 + rr) * K + gsw;
  const unsigned short* Br1 = Bt + (size_t)(n0 + rr + 64) * K + gsw;
  unsigned short* la0 = lsA + w * 512;
  unsigned short* la1 = lsA + 2048 + w * 512;
  unsigned short* lb0 = lsB + w * 512;
  unsigned short* lb1 = lsB + 2048 + w * 512;

  f32x4 acc[4][4];
#pragma unroll
  for (int i = 0; i < 4; i++)
#pragma unroll
    for (int j = 0; j < 4; j++) acc[i][j] = (f32x4){0.f, 0.f, 0.f, 0.f};

  gload16(Ar0, la0); gload16(Ar1, la1);
  gload16(Br0, lb0); gload16(Br1, lb1);

  for (int kt = 32; kt <= K; kt += 32) {
    __syncthreads();   // drains vmcnt -> tile ready
    bf16x8 af[4], bg[4];
#pragma unroll
    for (int i = 0; i < 4; i++) {
      int rm = wr * 64 + i * 16 + l16;
      af[i] = *(const bf16x8*)(lsA + rm * 32 + ((kq ^ (rm & 3)) * 8));
      int rn = wc * 64 + i * 16 + l16;
      bg[i] = *(const bf16x8*)(lsB + rn * 32 + ((kq ^ (rn & 3)) * 8));
    }
#pragma unroll
    for (int i = 0; i < 4; i++)
#pragma unroll
      for (int j = 0; j < 4; j++)
        acc[i][j] = __builtin_amdgcn_mfma_f32_16x16x32_bf16(af[i], bg[j], acc[i][j], 0, 0, 0);
    __syncthreads();
    if (kt < K) {
      gload16(Ar0 + kt, la0); gload16(Ar1 + kt, la1);
      gload16(Br0 + kt, lb0); gload16(Br1 + kt, lb1);
    }
  }
#pragma unroll
  for (int i = 0; i < 4; i++)
#pragma unroll
    for (int j = 0; j < 4; j++)
#pragma unroll
      for (int r = 0; r < 4; r++) {
        int m = m0 + wr * 64 + i * 16 + kq * 4 + r;
        int n = n0 + wc * 64 + j * 16 + l16;
        if constexpr (sizeof(OutT) == 2)
          C[(size_t)m * N + n] = (OutT)f2b(acc[i][j][r]);
        else
          C[(size_t)m * N + n] = (OutT)acc[i][j][r];
      }
}

// ---------------- dt projection (fp32) + softplus + dA -----------------------
__global__ __launch_bounds__(256) void dt_kernel(const float* __restrict__ hs,
                                                 const float* __restrict__ Wdt,
                                                 const float* __restrict__ dtb,
                                                 const float* __restrict__ alog,
                                                 float2* __restrict__ dAdt) {
  int w = threadIdx.x >> 6, h = threadIdx.x & 63;
  int r0 = blockIdx.x * 16 + w * 4;
  const float* h0 = hs + (size_t)r0 * HID;
  float a0 = 0.f, a1 = 0.f, a2 = 0.f, a3 = 0.f;
  for (int k = 0; k < HID; k += 4) {
    float4 x0 = *(const float4*)(h0 + k);
    float4 x1 = *(const float4*)(h0 + HID + k);
    float4 x2 = *(const float4*)(h0 + 2 * HID + k);
    float4 x3 = *(const float4*)(h0 + 3 * HID + k);
    float w0 = Wdt[(k + 0) * NH + h], w1 = Wdt[(k + 1) * NH + h];
    float w2 = Wdt[(k + 2) * NH + h], w3 = Wdt[(k + 3) * NH + h];
    a0 = fmaf(x0.w, w3, fmaf(x0.z, w2, fmaf(x0.y, w1, fmaf(x0.x, w0, a0))));
    a1 = fmaf(x1.w, w3, fmaf(x1.z, w2, fmaf(x1.y, w1, fmaf(x1.x, w0, a1))));
    a2 = fmaf(x2.w, w3, fmaf(x2.z, w2, fmaf(x2.y, w1, fmaf(x2.x, w0, a2))));
    a3 = fmaf(x3.w, w3, fmaf(x3.z, w2, fmaf(x3.y, w1, fmaf(x3.x, w0, a3))));
  }
  float A = -expf(alog[h]);
  float bias = dtb[h];
  float acc[4] = {a0, a1, a2, a3};
#pragma unroll
  for (int r = 0; r < 4; r++) {
    float v = acc[r] + bias;
    float dtv = (v > 20.f) ? v : log1pf(expf(v));
    float dA = expf(dtv * A);
    float2 o; o.x = dA; o.y = dtv;
    dAdt[(size_t)(r0 + r) * NH + h] = o;
  }
}

// ---------------- causal depthwise conv (K=4) + bias + SiLU (bf16 io) --------
__global__ __launch_bounds__(256) void conv_silu_k(const unsigned short* __restrict__ gin,
                                                   const float* __restrict__ cw,
                                                   const float* __restrict__ cb,
                                                   unsigned short* __restrict__ out) {
  int idx = blockIdx.x * 256 + threadIdx.x;
  int c = (idx % (CONVD / 4)) * 4;
  int row = idx / (CONVD / 4);
  int t = row & (S_LEN - 1);
  const unsigned short* src = gin + (size_t)row * NPROJ + INTER + c;
  float wv[4][4];
#pragma unroll
  for (int i = 0; i < 4; i++) {
    float4 v = *(const float4*)(cw + (size_t)(c + i) * 4);
    wv[i][0] = v.x; wv[i][1] = v.y; wv[i][2] = v.z; wv[i][3] = v.w;
  }
  float4 a = *(const float4*)(cb + c);
#pragma unroll
  for (int k = 0; k < 4; k++) {
    int off = k - 3;
    if (t + off >= 0) {
      ushort4 v = *(const ushort4*)(src + (long)off * NPROJ);
      a.x = fmaf(b2f(v.x), wv[0][k], a.x);
      a.y = fmaf(b2f(v.y), wv[1][k], a.y);
      a.z = fmaf(b2f(v.z), wv[2][k], a.z);
      a.w = fmaf(b2f(v.w), wv[3][k], a.w);
    }
  }
  a.x = a.x / (1.f + expf(-a.x));
  a.y = a.y / (1.f + expf(-a.y));
  a.z = a.z / (1.f + expf(-a.z));
  a.w = a.w / (1.f + expf(-a.w));
  ushort4 o;
  o.x = f2b(a.x); o.y = f2b(a.y); o.z = f2b(a.z); o.w = f2b(a.w);
  *(ushort4*)(out + (size_t)row * CONVD + c) = o;
}

// ---------------- selective SSM scan (bf16 in, bf16 out) ---------------------
// grid 256 = (b,h,dhalf); block 1024: thread=(d_local 0..31, n_thread 0..31),
// 4 states/thread in registers; y reduced over 32 lanes via shfl_xor.
__global__ __launch_bounds__(1024) void scan_k(const unsigned short* __restrict__ xbcc,
                                               const float2* __restrict__ dAdt,
                                               unsigned short* __restrict__ y) {
  int blk = blockIdx.x;
  int dh = blk & 1, h = (blk >> 1) & 63, b = blk >> 7;
  int tid = threadIdx.x;
  int dl = tid >> 5, nt = tid & 31;
  int d = dh * 32 + dl;
  int g = h >> 3;
  const unsigned short* xp = xbcc + (size_t)b * S_LEN * CONVD + h * HD + d;
  const ushort4* Bp = (const ushort4*)(xbcc + (size_t)b * S_LEN * CONVD + INTER + g * NST) + nt;
  const ushort4* Cp = (const ushort4*)(xbcc + (size_t)b * S_LEN * CONVD + INTER + GN + g * NST) + nt;
  const float2* ap = dAdt + (size_t)b * S_LEN * NH + h;
  unsigned short* yp = y + (size_t)b * S_LEN * INTER + h * HD + d;
  float s0 = 0.f, s1 = 0.f, s2 = 0.f, s3 = 0.f;
  for (int t = 0; t < S_LEN; ++t) {
    float2 ad = *ap;
    float xv = b2f(*xp);
    ushort4 Bu = *Bp;
    ushort4 Cu = *Cp;
    float dtx = ad.y * xv;
    s0 = fmaf(ad.x, s0, dtx * b2f(Bu.x));
    s1 = fmaf(ad.x, s1, dtx * b2f(Bu.y));
    s2 = fmaf(ad.x, s2, dtx * b2f(Bu.z));
    s3 = fmaf(ad.x, s3, dtx * b2f(Bu.w));
    float yv = fmaf(s3, b2f(Cu.w), fmaf(s2, b2f(Cu.z), fmaf(s1, b2f(Cu.y), s0 * b2f(Cu.x))));
    yv += __shfl_xor(yv, 1);
    yv += __shfl_xor(yv, 2);
    yv += __shfl_xor(yv, 4);
    yv += __shfl_xor(yv, 8);
    yv += __shfl_xor(yv, 16);
    if (nt == 0) *yp = f2b(yv);
    ap += NH; xp += CONVD; Bp += CONVD / 4; Cp += CONVD / 4; yp += INTER;
  }
}

// ---------------- gated RMSNorm (+ D*x skip) -> bf16 -------------------------
// block 256, each thread owns 16 consecutive channels (vectorized bf16 loads).
__global__ __launch_bounds__(256) void gatenorm_k(const unsigned short* __restrict__ y,
                                                  const unsigned short* __restrict__ xbcc,
                                                  const unsigned short* __restrict__ gin,
                                                  const float* __restrict__ Dp,
                                                  const float* __restrict__ nw,
                                                  unsigned short* __restrict__ nrm) {
  int row = blockIdx.x, tid = threadIdx.x;
  int c0 = tid * 16;
  const unsigned short* yr = y + (size_t)row * INTER + c0;
  const unsigned short* xr = xbcc + (size_t)row * CONVD + c0;
  const unsigned short* gr = gin + (size_t)row * NPROJ + c0;
  float Dv = Dp[c0 >> 6];
  uint4 yv[2], xv[2], gg[2];
  yv[0] = *(const uint4*)yr; yv[1] = *(const uint4*)(yr + 8);
  xv[0] = *(const uint4*)xr; xv[1] = *(const uint4*)(xr + 8);
  gg[0] = *(const uint4*)gr; gg[1] = *(const uint4*)(gr + 8);
  float yf[16], xf[16], gf[16];
#pragma unroll
  for (int j = 0; j < 2; j++) {
    const unsigned* yu = (const unsigned*)&yv[j];
    const unsigned* xu = (const unsigned*)&xv[j];
    const unsigned* gu = (const unsigned*)&gg[j];
#pragma unroll
    for (int q = 0; q < 4; q++) {
      unpack2(yu[q], yf[j * 8 + q * 2], yf[j * 8 + q * 2 + 1]);
      unpack2(xu[q], xf[j * 8 + q * 2], xf[j * 8 + q * 2 + 1]);
      unpack2(gu[q], gf[j * 8 + q * 2], gf[j * 8 + q * 2 + 1]);
    }
  }
  float gv[16];
  float ss = 0.f;
#pragma unroll
  for (int i = 0; i < 16; i++) {
    float gt = gf[i];
    float v = (yf[i] + Dv * xf[i]) * (gt / (1.f + expf(-gt)));
    gv[i] = v;
    ss = fmaf(v, v, ss);
  }
#pragma unroll
  for (int m = 1; m < 64; m <<= 1) ss += __shfl_xor(ss, m);
  __shared__ float red[4];
  if ((tid & 63) == 0) red[tid >> 6] = ss;
  __syncthreads();
  float scale = rsqrtf((red[0] + red[1] + red[2] + red[3]) * (1.f / INTER) + 1e-5f);
  unsigned short ob[16];
#pragma unroll
  for (int i = 0; i < 16; i++) ob[i] = f2b(gv[i] * scale * nw[c0 + i]);
  unsigned short* op = nrm + (size_t)row * INTER + c0;
  *(uint4*)op = *(uint4*)ob;
  *(uint4*)(op + 8) = *(uint4*)(ob + 8);
}

extern "C" void kernel_launch(void* const* d_in, const int* in_sizes, int n_in,
                              void* d_out, int out_size, void* d_ws, size_t ws_size,
                              hipStream_t stream) {
  const float* hs   = (const float*)d_in[0];
  const float* Wz   = (const float*)d_in[1];
  const float* Wx   = (const float*)d_in[2];
  const float* WB   = (const float*)d_in[3];
  const float* WC   = (const float*)d_in[4];
  const float* Wdt  = (const float*)d_in[5];
  const float* cw   = (const float*)d_in[6];
  const float* cb   = (const float*)d_in[7];
  const float* dtb  = (const float*)d_in[8];
  const float* alog = (const float*)d_in[9];
  const float* Dp   = (const float*)d_in[10];
  const float* nw   = (const float*)d_in[11];
  const float* Wout = (const float*)d_in[12];
  float* outp = (float*)d_out;

  // Workspace layout, peak 245,366,784 B (~234 MiB). All intermediates bf16.
  // nrm aliases [hsb | Wt1 head] - both dead after GEMM-1.
  char* ws = (char*)d_ws;
  unsigned short* hsb  = (unsigned short*)(ws);                  // 16 MiB
  unsigned short* Wt1  = (unsigned short*)(ws + 16777216ull);    // 40 MiB
  unsigned short* WoT  = (unsigned short*)(ws + 58720256ull);    // 16 MiB
  unsigned short* g1   = (unsigned short*)(ws + 75497472ull);    // 80 MiB bf16
  unsigned short* xbcc = (unsigned short*)(ws + 159383552ull);   // 48 MiB bf16
  float2*         dAdt = (float2*)(ws + 209715200ull);           // 2 MiB f32
  unsigned short* yb   = (unsigned short*)(ws + 211812352ull);   // 32 MiB bf16
  unsigned short* nrm  = (unsigned short*)(ws);                  // 32 MiB (alias)

  cast_k<<<(ROWS * HID / 4) / 256, 256, 0, stream>>>(hs, hsb);
  tcast_k<<<dim3(INTER / 64, HID / 64), 256, 0, stream>>>(Wz, Wt1, HID, INTER);
  tcast_k<<<dim3(INTER / 64, HID / 64), 256, 0, stream>>>(Wx, Wt1 + (size_t)INTER * HID, HID, INTER);
  tcast_k<<<dim3(GN / 64, HID / 64), 256, 0, stream>>>(WB, Wt1 + (size_t)2 * INTER * HID, HID, GN);
  tcast_k<<<dim3(GN / 64, HID / 64), 256, 0, stream>>>(WC, Wt1 + (size_t)(2 * INTER + GN) * HID, HID, GN);
  tcast_k<<<dim3(HID / 64, INTER / 64), 256, 0, stream>>>(Wout, WoT, INTER, HID);

  gemm_bt<unsigned short><<<dim3(NPROJ / 128, ROWS / 128), 256, 0, stream>>>(hsb, Wt1, g1, ROWS, NPROJ, HID);
  dt_kernel<<<ROWS / 16, 256, 0, stream>>>(hs, Wdt, dtb, alog, dAdt);
  conv_silu_k<<<(ROWS * (CONVD / 4)) / 256, 256, 0, stream>>>(g1, cw, cb, xbcc);
  scan_k<<<256, 1024, 0, stream>>>(xbcc, dAdt, yb);
  gatenorm_k<<<ROWS, 256, 0, stream>>>(yb, xbcc, g1, Dp, nw, nrm);
  gemm_bt<float><<<dim3(HID / 128, ROWS / 128), 256, 0, stream>>>(nrm, WoT, outp, ROWS, HID, INTER);
}

// Round 6
// 1598.650 us; speedup vs baseline: 1.2430x; 1.2430x over previous
//
#include <hip/hip_runtime.h>

#define HID   2048
#define S_LEN 2048
#define NBATCH 2
#define ROWS  (NBATCH*S_LEN)      // 4096
#define INTER 4096
#define GN    1024
#define NPROJ (2*INTER+2*GN)      // 10240
#define CONVD 6144
#define NH    64
#define HD    64
#define NST   128

typedef __attribute__((ext_vector_type(8))) short bf16x8;
typedef __attribute__((ext_vector_type(4))) float f32x4;

__device__ __forceinline__ unsigned short f2b(float f) {
  union { float f; unsigned u; } a; a.f = f;
  unsigned u = a.u;
  unsigned r = (u + 0x7fffu + ((u >> 16) & 1u)) >> 16;
  return (unsigned short)r;
}

__device__ __forceinline__ float b2f(unsigned short u) {
  union { unsigned u; float f; } a; a.u = ((unsigned)u) << 16; return a.f;
}

__device__ __forceinline__ void unpack2(unsigned u, float& lo, float& hi) {
  union { unsigned u; float f; } a, b;
  a.u = u << 16; b.u = u & 0xffff0000u;
  lo = a.f; hi = b.f;
}

__device__ __forceinline__ void gload16(const void* g, void* l) {
  __builtin_amdgcn_global_load_lds(
      (const __attribute__((address_space(1))) void*)g,
      (__attribute__((address_space(3))) void*)l, 16, 0, 0);
}

// ---------------- elementwise cast f32 -> bf16 (row-major kept) --------------
__global__ __launch_bounds__(256) void cast_k(const float* __restrict__ src,
                                              unsigned short* __restrict__ dst) {
  int i = blockIdx.x * 256 + threadIdx.x;
  float4 v = ((const float4*)src)[i];
  ushort4 o;
  o.x = f2b(v.x); o.y = f2b(v.y); o.z = f2b(v.z); o.w = f2b(v.w);
  ((ushort4*)dst)[i] = o;
}

// ---------------- transpose-cast: src f32 [R][Cc] -> dst bf16 [Cc][R] --------
__global__ __launch_bounds__(256) void tcast_k(const float* __restrict__ src,
                                               unsigned short* __restrict__ dst,
                                               int R, int Cc) {
  __shared__ unsigned short tile[64][65];
  int c0 = blockIdx.x * 64, r0 = blockIdx.y * 64;
  int tid = threadIdx.x;
  int tr = tid >> 4, tc = (tid & 15) * 4;
#pragma unroll
  for (int i = 0; i < 4; i++) {
    int r = tr + i * 16;
    float4 v = *(const float4*)(src + (size_t)(r0 + r) * Cc + c0 + tc);
    tile[r][tc + 0] = f2b(v.x); tile[r][tc + 1] = f2b(v.y);
    tile[r][tc + 2] = f2b(v.z); tile[r][tc + 3] = f2b(v.w);
  }
  __syncthreads();
#pragma unroll
  for (int i = 0; i < 4; i++) {
    int cc = tr + i * 16;
    ushort4 o;
    o.x = tile[tc + 0][cc]; o.y = tile[tc + 1][cc];
    o.z = tile[tc + 2][cc]; o.w = tile[tc + 3][cc];
    *(ushort4*)(dst + (size_t)(c0 + cc) * R + r0 + tc) = o;
  }
}

// ---------------- bf16 GEMM: C[M,N] = A[M,K] * Bt[N,K]^T ---------------------
// 128x128 tile, BK=32, 256 thr (2x2 waves of 64x64), global_load_lds w=16,
// involution XOR-swizzle (src granule pre-swizzled, linear LDS, swizzled read).
template <typename OutT>
__global__ __launch_bounds__(256) void gemm_bt(const unsigned short* __restrict__ A,
                                               const unsigned short* __restrict__ Bt,
                                               OutT* __restrict__ C,
                                               int M, int N, int K) {
  __shared__ unsigned short lsA[128 * 32];
  __shared__ unsigned short lsB[128 * 32];
  const int tid = threadIdx.x;
  const int w = tid >> 6, lane = tid & 63;
  const int m0 = blockIdx.y * 128, n0 = blockIdx.x * 128;
  const int wr = w >> 1, wc = w & 1;
  const int l16 = lane & 15, kq = lane >> 4;

  const int rr = tid >> 2;
  const int gl = tid & 3;
  const int gsw = ((gl ^ (rr & 3)) * 8);              // swizzled src granule (elems)
  const unsigned short* Ar0 = A + (size_t)(m0 + rr) * K + gsw;
  const unsigned short* Ar1 = A + (size_t)(m0 + rr + 64) * K + gsw;
  const unsigned short* Br0 = Bt + (size_t)(n0 + rr) * K + gsw;
  const unsigned short* Br1 = Bt + (size_t)(n0 + rr + 64) * K + gsw;
  unsigned short* la0 = lsA + w * 512;
  unsigned short* la1 = lsA + 2048 + w * 512;
  unsigned short* lb0 = lsB + w * 512;
  unsigned short* lb1 = lsB + 2048 + w * 512;

  f32x4 acc[4][4];
#pragma unroll
  for (int i = 0; i < 4; i++)
#pragma unroll
    for (int j = 0; j < 4; j++) acc[i][j] = (f32x4){0.f, 0.f, 0.f, 0.f};

  gload16(Ar0, la0); gload16(Ar1, la1);
  gload16(Br0, lb0); gload16(Br1, lb1);

  for (int kt = 32; kt <= K; kt += 32) {
    __syncthreads();   // drains vmcnt -> tile ready
    bf16x8 af[4], bg[4];
#pragma unroll
    for (int i = 0; i < 4; i++) {
      int rm = wr * 64 + i * 16 + l16;
      af[i] = *(const bf16x8*)(lsA + rm * 32 + ((kq ^ (rm & 3)) * 8));
      int rn = wc * 64 + i * 16 + l16;
      bg[i] = *(const bf16x8*)(lsB + rn * 32 + ((kq ^ (rn & 3)) * 8));
    }
#pragma unroll
    for (int i = 0; i < 4; i++)
#pragma unroll
      for (int j = 0; j < 4; j++)
        acc[i][j] = __builtin_amdgcn_mfma_f32_16x16x32_bf16(af[i], bg[j], acc[i][j], 0, 0, 0);
    __syncthreads();
    if (kt < K) {
      gload16(Ar0 + kt, la0); gload16(Ar1 + kt, la1);
      gload16(Br0 + kt, lb0); gload16(Br1 + kt, lb1);
    }
  }
#pragma unroll
  for (int i = 0; i < 4; i++)
#pragma unroll
    for (int j = 0; j < 4; j++)
#pragma unroll
      for (int r = 0; r < 4; r++) {
        int m = m0 + wr * 64 + i * 16 + kq * 4 + r;
        int n = n0 + wc * 64 + j * 16 + l16;
        if constexpr (sizeof(OutT) == 2)
          C[(size_t)m * N + n] = (OutT)f2b(acc[i][j][r]);
        else
          C[(size_t)m * N + n] = (OutT)acc[i][j][r];
      }
}

// ---------------- dt projection (fp32) + softplus + dA -----------------------
__global__ __launch_bounds__(256) void dt_kernel(const float* __restrict__ hs,
                                                 const float* __restrict__ Wdt,
                                                 const float* __restrict__ dtb,
                                                 const float* __restrict__ alog,
                                                 float2* __restrict__ dAdt) {
  int w = threadIdx.x >> 6, h = threadIdx.x & 63;
  int r0 = blockIdx.x * 16 + w * 4;
  const float* h0 = hs + (size_t)r0 * HID;
  float a0 = 0.f, a1 = 0.f, a2 = 0.f, a3 = 0.f;
  for (int k = 0; k < HID; k += 4) {
    float4 x0 = *(const float4*)(h0 + k);
    float4 x1 = *(const float4*)(h0 + HID + k);
    float4 x2 = *(const float4*)(h0 + 2 * HID + k);
    float4 x3 = *(const float4*)(h0 + 3 * HID + k);
    float w0 = Wdt[(k + 0) * NH + h], w1 = Wdt[(k + 1) * NH + h];
    float w2 = Wdt[(k + 2) * NH + h], w3 = Wdt[(k + 3) * NH + h];
    a0 = fmaf(x0.w, w3, fmaf(x0.z, w2, fmaf(x0.y, w1, fmaf(x0.x, w0, a0))));
    a1 = fmaf(x1.w, w3, fmaf(x1.z, w2, fmaf(x1.y, w1, fmaf(x1.x, w0, a1))));
    a2 = fmaf(x2.w, w3, fmaf(x2.z, w2, fmaf(x2.y, w1, fmaf(x2.x, w0, a2))));
    a3 = fmaf(x3.w, w3, fmaf(x3.z, w2, fmaf(x3.y, w1, fmaf(x3.x, w0, a3))));
  }
  float A = -expf(alog[h]);
  float bias = dtb[h];
  float acc[4] = {a0, a1, a2, a3};
#pragma unroll
  for (int r = 0; r < 4; r++) {
    float v = acc[r] + bias;
    float dtv = (v > 20.f) ? v : log1pf(expf(v));
    float dA = expf(dtv * A);
    float2 o; o.x = dA; o.y = dtv;
    dAdt[(size_t)(r0 + r) * NH + h] = o;
  }
}

// ---------------- causal depthwise conv (K=4) + bias + SiLU (bf16 io) --------
__global__ __launch_bounds__(256) void conv_silu_k(const unsigned short* __restrict__ gin,
                                                   const float* __restrict__ cw,
                                                   const float* __restrict__ cb,
                                                   unsigned short* __restrict__ out) {
  int idx = blockIdx.x * 256 + threadIdx.x;
  int c = (idx % (CONVD / 4)) * 4;
  int row = idx / (CONVD / 4);
  int t = row & (S_LEN - 1);
  const unsigned short* src = gin + (size_t)row * NPROJ + INTER + c;
  float wv[4][4];
#pragma unroll
  for (int i = 0; i < 4; i++) {
    float4 v = *(const float4*)(cw + (size_t)(c + i) * 4);
    wv[i][0] = v.x; wv[i][1] = v.y; wv[i][2] = v.z; wv[i][3] = v.w;
  }
  float4 a = *(const float4*)(cb + c);
#pragma unroll
  for (int k = 0; k < 4; k++) {
    int off = k - 3;
    if (t + off >= 0) {
      ushort4 v = *(const ushort4*)(src + (long)off * NPROJ);
      a.x = fmaf(b2f(v.x), wv[0][k], a.x);
      a.y = fmaf(b2f(v.y), wv[1][k], a.y);
      a.z = fmaf(b2f(v.z), wv[2][k], a.z);
      a.w = fmaf(b2f(v.w), wv[3][k], a.w);
    }
  }
  a.x = a.x / (1.f + expf(-a.x));
  a.y = a.y / (1.f + expf(-a.y));
  a.z = a.z / (1.f + expf(-a.z));
  a.w = a.w / (1.f + expf(-a.w));
  ushort4 o;
  o.x = f2b(a.x); o.y = f2b(a.y); o.z = f2b(a.z); o.w = f2b(a.w);
  *(ushort4*)(out + (size_t)row * CONVD + c) = o;
}

// ---------------- selective SSM scan (bf16 in, bf16 out) ---------------------
// grid 256 = (b,h,dhalf); block 1024: thread=(d_local 0..31, n_thread 0..31),
// 4 states/thread in registers; y reduced over 32 lanes via shfl_xor.
// 4-deep explicit prefetch: loads for step t+4 issue while computing step t,
// so the recurrence never waits on L3/HBM latency (addresses are t-independent).
__global__ __launch_bounds__(1024) void scan_k(const unsigned short* __restrict__ xbcc,
                                               const float2* __restrict__ dAdt,
                                               unsigned short* __restrict__ y) {
  int blk = blockIdx.x;
  int dh = blk & 1, h = (blk >> 1) & 63, b = blk >> 7;
  int tid = threadIdx.x;
  int dl = tid >> 5, nt = tid & 31;
  int d = dh * 32 + dl;
  int g = h >> 3;
  const unsigned short* xpb = xbcc + (size_t)b * S_LEN * CONVD + h * HD + d;
  const ushort4* Bpb = (const ushort4*)(xbcc + (size_t)b * S_LEN * CONVD + INTER + g * NST) + nt;
  const ushort4* Cpb = (const ushort4*)(xbcc + (size_t)b * S_LEN * CONVD + INTER + GN + g * NST) + nt;
  const float2* apb = dAdt + (size_t)b * S_LEN * NH + h;
  unsigned short* ypb = y + (size_t)b * S_LEN * INTER + h * HD + d;

  float s0 = 0.f, s1 = 0.f, s2 = 0.f, s3 = 0.f;

  float2 ad[4]; unsigned short xu[4]; ushort4 Bu[4], Cu[4];
#pragma unroll
  for (int I = 0; I < 4; I++) {
    ad[I] = apb[(size_t)I * NH];
    xu[I] = xpb[(size_t)I * CONVD];
    Bu[I] = Bpb[(size_t)I * (CONVD / 4)];
    Cu[I] = Cpb[(size_t)I * (CONVD / 4)];
  }

  for (int t = 0; t < S_LEN; t += 4) {
#pragma unroll
    for (int I = 0; I < 4; I++) {
      // consume set I (holds step t+I)
      float2 a2 = ad[I];
      float xv = b2f(xu[I]);
      ushort4 Bv = Bu[I], Cv = Cu[I];
      // issue prefetch for step t+I+4 immediately (clamped at tail)
      int tn = t + I + 4; tn = tn < S_LEN ? tn : S_LEN - 1;
      ad[I] = apb[(size_t)tn * NH];
      xu[I] = xpb[(size_t)tn * CONVD];
      Bu[I] = Bpb[(size_t)tn * (CONVD / 4)];
      Cu[I] = Cpb[(size_t)tn * (CONVD / 4)];
      // recurrence + output
      float dtx = a2.y * xv;
      s0 = fmaf(a2.x, s0, dtx * b2f(Bv.x));
      s1 = fmaf(a2.x, s1, dtx * b2f(Bv.y));
      s2 = fmaf(a2.x, s2, dtx * b2f(Bv.z));
      s3 = fmaf(a2.x, s3, dtx * b2f(Bv.w));
      float yv = fmaf(s3, b2f(Cv.w), fmaf(s2, b2f(Cv.z), fmaf(s1, b2f(Cv.y), s0 * b2f(Cv.x))));
      yv += __shfl_xor(yv, 1);
      yv += __shfl_xor(yv, 2);
      yv += __shfl_xor(yv, 4);
      yv += __shfl_xor(yv, 8);
      yv += __shfl_xor(yv, 16);
      if (nt == 0) ypb[(size_t)(t + I) * INTER] = f2b(yv);
    }
  }
}

// ---------------- gated RMSNorm (+ D*x skip) -> bf16 -------------------------
// block 256, each thread owns 16 consecutive channels (vectorized bf16 loads).
__global__ __launch_bounds__(256) void gatenorm_k(const unsigned short* __restrict__ y,
                                                  const unsigned short* __restrict__ xbcc,
                                                  const unsigned short* __restrict__ gin,
                                                  const float* __restrict__ Dp,
                                                  const float* __restrict__ nw,
                                                  unsigned short* __restrict__ nrm) {
  int row = blockIdx.x, tid = threadIdx.x;
  int c0 = tid * 16;
  const unsigned short* yr = y + (size_t)row * INTER + c0;
  const unsigned short* xr = xbcc + (size_t)row * CONVD + c0;
  const unsigned short* gr = gin + (size_t)row * NPROJ + c0;
  float Dv = Dp[c0 >> 6];
  uint4 yv[2], xv[2], gg[2];
  yv[0] = *(const uint4*)yr; yv[1] = *(const uint4*)(yr + 8);
  xv[0] = *(const uint4*)xr; xv[1] = *(const uint4*)(xr + 8);
  gg[0] = *(const uint4*)gr; gg[1] = *(const uint4*)(gr + 8);
  float yf[16], xf[16], gf[16];
#pragma unroll
  for (int j = 0; j < 2; j++) {
    const unsigned* yu = (const unsigned*)&yv[j];
    const unsigned* xu = (const unsigned*)&xv[j];
    const unsigned* gu = (const unsigned*)&gg[j];
#pragma unroll
    for (int q = 0; q < 4; q++) {
      unpack2(yu[q], yf[j * 8 + q * 2], yf[j * 8 + q * 2 + 1]);
      unpack2(xu[q], xf[j * 8 + q * 2], xf[j * 8 + q * 2 + 1]);
      unpack2(gu[q], gf[j * 8 + q * 2], gf[j * 8 + q * 2 + 1]);
    }
  }
  float gv[16];
  float ss = 0.f;
#pragma unroll
  for (int i = 0; i < 16; i++) {
    float gt = gf[i];
    float v = (yf[i] + Dv * xf[i]) * (gt / (1.f + expf(-gt)));
    gv[i] = v;
    ss = fmaf(v, v, ss);
  }
#pragma unroll
  for (int m = 1; m < 64; m <<= 1) ss += __shfl_xor(ss, m);
  __shared__ float red[4];
  if ((tid & 63) == 0) red[tid >> 6] = ss;
  __syncthreads();
  float scale = rsqrtf((red[0] + red[1] + red[2] + red[3]) * (1.f / INTER) + 1e-5f);
  unsigned short ob[16];
#pragma unroll
  for (int i = 0; i < 16; i++) ob[i] = f2b(gv[i] * scale * nw[c0 + i]);
  unsigned short* op = nrm + (size_t)row * INTER + c0;
  *(uint4*)op = *(uint4*)ob;
  *(uint4*)(op + 8) = *(uint4*)(ob + 8);
}

extern "C" void kernel_launch(void* const* d_in, const int* in_sizes, int n_in,
                              void* d_out, int out_size, void* d_ws, size_t ws_size,
                              hipStream_t stream) {
  const float* hs   = (const float*)d_in[0];
  const float* Wz   = (const float*)d_in[1];
  const float* Wx   = (const float*)d_in[2];
  const float* WB   = (const float*)d_in[3];
  const float* WC   = (const float*)d_in[4];
  const float* Wdt  = (const float*)d_in[5];
  const float* cw   = (const float*)d_in[6];
  const float* cb   = (const float*)d_in[7];
  const float* dtb  = (const float*)d_in[8];
  const float* alog = (const float*)d_in[9];
  const float* Dp   = (const float*)d_in[10];
  const float* nw   = (const float*)d_in[11];
  const float* Wout = (const float*)d_in[12];
  float* outp = (float*)d_out;

  // Workspace layout, peak 245,366,784 B (~234 MiB). All intermediates bf16.
  // nrm aliases [hsb | Wt1 head] - both dead after GEMM-1.
  char* ws = (char*)d_ws;
  unsigned short* hsb  = (unsigned short*)(ws);                  // 16 MiB
  unsigned short* Wt1  = (unsigned short*)(ws + 16777216ull);    // 40 MiB
  unsigned short* WoT  = (unsigned short*)(ws + 58720256ull);    // 16 MiB
  unsigned short* g1   = (unsigned short*)(ws + 75497472ull);    // 80 MiB bf16
  unsigned short* xbcc = (unsigned short*)(ws + 159383552ull);   // 48 MiB bf16
  float2*         dAdt = (float2*)(ws + 209715200ull);           // 2 MiB f32
  unsigned short* yb   = (unsigned short*)(ws + 211812352ull);   // 32 MiB bf16
  unsigned short* nrm  = (unsigned short*)(ws);                  // 32 MiB (alias)

  cast_k<<<(ROWS * HID / 4) / 256, 256, 0, stream>>>(hs, hsb);
  tcast_k<<<dim3(INTER / 64, HID / 64), 256, 0, stream>>>(Wz, Wt1, HID, INTER);
  tcast_k<<<dim3(INTER / 64, HID / 64), 256, 0, stream>>>(Wx, Wt1 + (size_t)INTER * HID, HID, INTER);
  tcast_k<<<dim3(GN / 64, HID / 64), 256, 0, stream>>>(WB, Wt1 + (size_t)2 * INTER * HID, HID, GN);
  tcast_k<<<dim3(GN / 64, HID / 64), 256, 0, stream>>>(WC, Wt1 + (size_t)(2 * INTER + GN) * HID, HID, GN);
  tcast_k<<<dim3(HID / 64, INTER / 64), 256, 0, stream>>>(Wout, WoT, INTER, HID);

  gemm_bt<unsigned short><<<dim3(NPROJ / 128, ROWS / 128), 256, 0, stream>>>(hsb, Wt1, g1, ROWS, NPROJ, HID);
  dt_kernel<<<ROWS / 16, 256, 0, stream>>>(hs, Wdt, dtb, alog, dAdt);
  conv_silu_k<<<(ROWS * (CONVD / 4)) / 256, 256, 0, stream>>>(g1, cw, cb, xbcc);
  scan_k<<<256, 1024, 0, stream>>>(xbcc, dAdt, yb);
  gatenorm_k<<<ROWS, 256, 0, stream>>>(yb, xbcc, g1, Dp, nw, nrm);
  gemm_bt<float><<<dim3(HID / 128, ROWS / 128), 256, 0, stream>>>(nrm, WoT, outp, ROWS, HID, INTER);
}

// Round 9
// 890.704 us; speedup vs baseline: 2.2310x; 1.7948x over previous
//
#include <hip/hip_runtime.h>

#define HID   2048
#define S_LEN 2048
#define NBATCH 2
#define ROWS  (NBATCH*S_LEN)      // 4096
#define INTER 4096
#define GN    1024
#define NPROJ (2*INTER+2*GN)      // 10240
#define CONVD 6144
#define NH    64
#define HD    64
#define NST   128
#define CHL   128                 // SSD chunk length
#define NCH   16                  // chunks per sequence

typedef __attribute__((ext_vector_type(8))) short bf16x8;
typedef __attribute__((ext_vector_type(4))) float f32x4;

__device__ __forceinline__ unsigned short f2b(float f) {
  union { float f; unsigned u; } a; a.f = f;
  unsigned u = a.u;
  unsigned r = (u + 0x7fffu + ((u >> 16) & 1u)) >> 16;
  return (unsigned short)r;
}

__device__ __forceinline__ float b2f(unsigned short u) {
  union { unsigned u; float f; } a; a.u = ((unsigned)u) << 16; return a.f;
}

__device__ __forceinline__ void unpack2(unsigned u, float& lo, float& hi) {
  union { unsigned u; float f; } a, b;
  a.u = u << 16; b.u = u & 0xffff0000u;
  lo = a.f; hi = b.f;
}

__device__ __forceinline__ void gload16(const void* g, void* l) {
  __builtin_amdgcn_global_load_lds(
      (const __attribute__((address_space(1))) void*)g,
      (__attribute__((address_space(3))) void*)l, 16, 0, 0);
}

// ---------------- elementwise cast f32 -> bf16 -------------------------------
__global__ __launch_bounds__(256) void cast_k(const float* __restrict__ src,
                                              unsigned short* __restrict__ dst) {
  int i = blockIdx.x * 256 + threadIdx.x;
  float4 v = ((const float4*)src)[i];
  ushort4 o;
  o.x = f2b(v.x); o.y = f2b(v.y); o.z = f2b(v.z); o.w = f2b(v.w);
  ((ushort4*)dst)[i] = o;
}

// ---------------- transpose-cast: src f32 [R][Cc] -> dst bf16 [Cc][R] --------
__global__ __launch_bounds__(256) void tcast_k(const float* __restrict__ src,
                                               unsigned short* __restrict__ dst,
                                               int R, int Cc) {
  __shared__ unsigned short tile[64][65];
  int c0 = blockIdx.x * 64, r0 = blockIdx.y * 64;
  int tid = threadIdx.x;
  int tr = tid >> 4, tc = (tid & 15) * 4;
#pragma unroll
  for (int i = 0; i < 4; i++) {
    int r = tr + i * 16;
    float4 v = *(const float4*)(src + (size_t)(r0 + r) * Cc + c0 + tc);
    tile[r][tc + 0] = f2b(v.x); tile[r][tc + 1] = f2b(v.y);
    tile[r][tc + 2] = f2b(v.z); tile[r][tc + 3] = f2b(v.w);
  }
  __syncthreads();
#pragma unroll
  for (int i = 0; i < 4; i++) {
    int cc = tr + i * 16;
    ushort4 o;
    o.x = tile[tc + 0][cc]; o.y = tile[tc + 1][cc];
    o.z = tile[tc + 2][cc]; o.w = tile[tc + 3][cc];
    *(ushort4*)(dst + (size_t)(c0 + cc) * R + r0 + tc) = o;
  }
}

// ---------------- bf16->bf16 transpose of B part: xbcc cols [4096,5120) ------
// -> BT [b][1024][2048]
__global__ __launch_bounds__(256) void transB_k(const unsigned short* __restrict__ xbcc,
                                                unsigned short* __restrict__ BT) {
  __shared__ unsigned short tile[64][66];
  int cb = blockIdx.x, tb = blockIdx.y, b = blockIdx.z;
  int ch0 = INTER + cb * 64, t0 = tb * 64;
  int tid = threadIdx.x;
  int tr = tid >> 4, tc = (tid & 15) * 4;
#pragma unroll
  for (int i = 0; i < 4; i++) {
    int r = tr + i * 16;
    ushort4 v = *(const ushort4*)(xbcc + (size_t)(b * S_LEN + t0 + r) * CONVD + ch0 + tc);
    tile[r][tc + 0] = v.x; tile[r][tc + 1] = v.y;
    tile[r][tc + 2] = v.z; tile[r][tc + 3] = v.w;
  }
  __syncthreads();
#pragma unroll
  for (int i = 0; i < 4; i++) {
    int cc = tr + i * 16;
    ushort4 o;
    o.x = tile[tc + 0][cc]; o.y = tile[tc + 1][cc];
    o.z = tile[tc + 2][cc]; o.w = tile[tc + 3][cc];
    *(ushort4*)(BT + (size_t)(b * GN + cb * 64 + cc) * S_LEN + t0 + tc) = o;
  }
}

// ---------------- bf16 GEMM (verified core) ----------------------------------
template <typename OutT>
__global__ __launch_bounds__(256) void gemm_bt(const unsigned short* __restrict__ A,
                                               const unsigned short* __restrict__ Bt,
                                               OutT* __restrict__ C,
                                               int M, int N, int K) {
  __shared__ unsigned short lsA[128 * 32];
  __shared__ unsigned short lsB[128 * 32];
  const int tid = threadIdx.x;
  const int w = tid >> 6, lane = tid & 63;
  const int m0 = blockIdx.y * 128, n0 = blockIdx.x * 128;
  const int wr = w >> 1, wc = w & 1;
  const int l16 = lane & 15, kq = lane >> 4;
  const int rr = tid >> 2;
  const int gl = tid & 3;
  const int gsw = ((gl ^ (rr & 3)) * 8);
  const unsigned short* Ar0 = A + (size_t)(m0 + rr) * K + gsw;
  const unsigned short* Ar1 = A + (size_t)(m0 + rr + 64) * K + gsw;
  const unsigned short* Br0 = Bt + (size_t)(n0 + rr) * K + gsw;
  const unsigned short* Br1 = Bt + (size_t)(n0 + rr + 64) * K + gsw;
  unsigned short* la0 = lsA + w * 512;
  unsigned short* la1 = lsA + 2048 + w * 512;
  unsigned short* lb0 = lsB + w * 512;
  unsigned short* lb1 = lsB + 2048 + w * 512;

  f32x4 acc[4][4];
#pragma unroll
  for (int i = 0; i < 4; i++)
#pragma unroll
    for (int j = 0; j < 4; j++) acc[i][j] = (f32x4){0.f, 0.f, 0.f, 0.f};

  gload16(Ar0, la0); gload16(Ar1, la1);
  gload16(Br0, lb0); gload16(Br1, lb1);

  for (int kt = 32; kt <= K; kt += 32) {
    __syncthreads();
    bf16x8 af[4], bg[4];
#pragma unroll
    for (int i = 0; i < 4; i++) {
      int rm = wr * 64 + i * 16 + l16;
      af[i] = *(const bf16x8*)(lsA + rm * 32 + ((kq ^ (rm & 3)) * 8));
      int rn = wc * 64 + i * 16 + l16;
      bg[i] = *(const bf16x8*)(lsB + rn * 32 + ((kq ^ (rn & 3)) * 8));
    }
#pragma unroll
    for (int i = 0; i < 4; i++)
#pragma unroll
      for (int j = 0; j < 4; j++)
        acc[i][j] = __builtin_amdgcn_mfma_f32_16x16x32_bf16(af[i], bg[j], acc[i][j], 0, 0, 0);
    __syncthreads();
    if (kt < K) {
      gload16(Ar0 + kt, la0); gload16(Ar1 + kt, la1);
      gload16(Br0 + kt, lb0); gload16(Br1 + kt, lb1);
    }
  }
#pragma unroll
  for (int i = 0; i < 4; i++)
#pragma unroll
    for (int j = 0; j < 4; j++)
#pragma unroll
      for (int r = 0; r < 4; r++) {
        int m = m0 + wr * 64 + i * 16 + kq * 4 + r;
        int n = n0 + wc * 64 + j * 16 + l16;
        if constexpr (sizeof(OutT) == 2)
          C[(size_t)m * N + n] = (OutT)f2b(acc[i][j][r]);
        else
          C[(size_t)m * N + n] = (OutT)acc[i][j][r];
      }
}

// ---------------- GEMM with split output: gate [M][4096] | xBC [M][6144] -----
__global__ __launch_bounds__(256) void gemm_split(const unsigned short* __restrict__ A,
                                                  const unsigned short* __restrict__ Bt,
                                                  unsigned short* __restrict__ gate,
                                                  unsigned short* __restrict__ xbcR,
                                                  int M, int N, int K) {
  __shared__ unsigned short lsA[128 * 32];
  __shared__ unsigned short lsB[128 * 32];
  const int tid = threadIdx.x;
  const int w = tid >> 6, lane = tid & 63;
  const int m0 = blockIdx.y * 128, n0 = blockIdx.x * 128;
  const int wr = w >> 1, wc = w & 1;
  const int l16 = lane & 15, kq = lane >> 4;
  const int rr = tid >> 2;
  const int gl = tid & 3;
  const int gsw = ((gl ^ (rr & 3)) * 8);
  const unsigned short* Ar0 = A + (size_t)(m0 + rr) * K + gsw;
  const unsigned short* Ar1 = A + (size_t)(m0 + rr + 64) * K + gsw;
  const unsigned short* Br0 = Bt + (size_t)(n0 + rr) * K + gsw;
  const unsigned short* Br1 = Bt + (size_t)(n0 + rr + 64) * K + gsw;
  unsigned short* la0 = lsA + w * 512;
  unsigned short* la1 = lsA + 2048 + w * 512;
  unsigned short* lb0 = lsB + w * 512;
  unsigned short* lb1 = lsB + 2048 + w * 512;

  f32x4 acc[4][4];
#pragma unroll
  for (int i = 0; i < 4; i++)
#pragma unroll
    for (int j = 0; j < 4; j++) acc[i][j] = (f32x4){0.f, 0.f, 0.f, 0.f};

  gload16(Ar0, la0); gload16(Ar1, la1);
  gload16(Br0, lb0); gload16(Br1, lb1);

  for (int kt = 32; kt <= K; kt += 32) {
    __syncthreads();
    bf16x8 af[4], bg[4];
#pragma unroll
    for (int i = 0; i < 4; i++) {
      int rm = wr * 64 + i * 16 + l16;
      af[i] = *(const bf16x8*)(lsA + rm * 32 + ((kq ^ (rm & 3)) * 8));
      int rn = wc * 64 + i * 16 + l16;
      bg[i] = *(const bf16x8*)(lsB + rn * 32 + ((kq ^ (rn & 3)) * 8));
    }
#pragma unroll
    for (int i = 0; i < 4; i++)
#pragma unroll
      for (int j = 0; j < 4; j++)
        acc[i][j] = __builtin_amdgcn_mfma_f32_16x16x32_bf16(af[i], bg[j], acc[i][j], 0, 0, 0);
    __syncthreads();
    if (kt < K) {
      gload16(Ar0 + kt, la0); gload16(Ar1 + kt, la1);
      gload16(Br0 + kt, lb0); gload16(Br1 + kt, lb1);
    }
  }
  if (n0 < INTER) {   // whole block in gate range (INTER = 32*128)
#pragma unroll
    for (int i = 0; i < 4; i++)
#pragma unroll
      for (int j = 0; j < 4; j++)
#pragma unroll
        for (int r = 0; r < 4; r++) {
          int m = m0 + wr * 64 + i * 16 + kq * 4 + r;
          int n = n0 + wc * 64 + j * 16 + l16;
          gate[(size_t)m * INTER + n] = f2b(acc[i][j][r]);
        }
  } else {
#pragma unroll
    for (int i = 0; i < 4; i++)
#pragma unroll
      for (int j = 0; j < 4; j++)
#pragma unroll
        for (int r = 0; r < 4; r++) {
          int m = m0 + wr * 64 + i * 16 + kq * 4 + r;
          int n = n0 + wc * 64 + j * 16 + l16 - INTER;
          xbcR[(size_t)m * CONVD + n] = f2b(acc[i][j][r]);
        }
  }
}

// ---------------- dt projection (fp32) + softplus: store (la = dt*A, dt) -----
__global__ __launch_bounds__(256) void dt_kernel(const float* __restrict__ hs,
                                                 const float* __restrict__ Wdt,
                                                 const float* __restrict__ dtb,
                                                 const float* __restrict__ alog,
                                                 float2* __restrict__ dAdt) {
  int w = threadIdx.x >> 6, h = threadIdx.x & 63;
  int r0 = blockIdx.x * 16 + w * 4;
  const float* h0 = hs + (size_t)r0 * HID;
  float a0 = 0.f, a1 = 0.f, a2 = 0.f, a3 = 0.f;
  for (int k = 0; k < HID; k += 4) {
    float4 x0 = *(const float4*)(h0 + k);
    float4 x1 = *(const float4*)(h0 + HID + k);
    float4 x2 = *(const float4*)(h0 + 2 * HID + k);
    float4 x3 = *(const float4*)(h0 + 3 * HID + k);
    float w0 = Wdt[(k + 0) * NH + h], w1 = Wdt[(k + 1) * NH + h];
    float w2 = Wdt[(k + 2) * NH + h], w3 = Wdt[(k + 3) * NH + h];
    a0 = fmaf(x0.w, w3, fmaf(x0.z, w2, fmaf(x0.y, w1, fmaf(x0.x, w0, a0))));
    a1 = fmaf(x1.w, w3, fmaf(x1.z, w2, fmaf(x1.y, w1, fmaf(x1.x, w0, a1))));
    a2 = fmaf(x2.w, w3, fmaf(x2.z, w2, fmaf(x2.y, w1, fmaf(x2.x, w0, a2))));
    a3 = fmaf(x3.w, w3, fmaf(x3.z, w2, fmaf(x3.y, w1, fmaf(x3.x, w0, a3))));
  }
  float A = -expf(alog[h]);
  float bias = dtb[h];
  float acc[4] = {a0, a1, a2, a3};
#pragma unroll
  for (int r = 0; r < 4; r++) {
    float v = acc[r] + bias;
    float dtv = (v > 20.f) ? v : log1pf(expf(v));
    float2 o; o.x = dtv * A; o.y = dtv;   // (la, dt)
    dAdt[(size_t)(r0 + r) * NH + h] = o;
  }
}

// ---------------- causal depthwise conv (K=4) + bias + SiLU (bf16 io) --------
__global__ __launch_bounds__(256) void conv_silu_k(const unsigned short* __restrict__ gin,
                                                   const float* __restrict__ cw,
                                                   const float* __restrict__ cb,
                                                   unsigned short* __restrict__ out) {
  int idx = blockIdx.x * 256 + threadIdx.x;
  int c = (idx % (CONVD / 4)) * 4;
  int row = idx / (CONVD / 4);
  int t = row & (S_LEN - 1);
  const unsigned short* src = gin + (size_t)row * CONVD + c;
  float wv[4][4];
#pragma unroll
  for (int i = 0; i < 4; i++) {
    float4 v = *(const float4*)(cw + (size_t)(c + i) * 4);
    wv[i][0] = v.x; wv[i][1] = v.y; wv[i][2] = v.z; wv[i][3] = v.w;
  }
  float4 a = *(const float4*)(cb + c);
#pragma unroll
  for (int k = 0; k < 4; k++) {
    int off = k - 3;
    if (t + off >= 0) {
      ushort4 v = *(const ushort4*)(src + (long)off * CONVD);
      a.x = fmaf(b2f(v.x), wv[0][k], a.x);
      a.y = fmaf(b2f(v.y), wv[1][k], a.y);
      a.z = fmaf(b2f(v.z), wv[2][k], a.z);
      a.w = fmaf(b2f(v.w), wv[3][k], a.w);
    }
  }
  a.x = a.x / (1.f + expf(-a.x));
  a.y = a.y / (1.f + expf(-a.y));
  a.z = a.z / (1.f + expf(-a.z));
  a.w = a.w / (1.f + expf(-a.w));
  ushort4 o;
  o.x = f2b(a.x); o.y = f2b(a.y); o.z = f2b(a.z); o.w = f2b(a.w);
  *(ushort4*)(out + (size_t)row * CONVD + c) = o;
}

// ---------------- per-chunk inclusive cumsum of la ---------------------------
// grid (b,h,c)=2048 x 128 thr; csum[bh][t]
__global__ __launch_bounds__(128) void csum_k(const float2* __restrict__ dAdt,
                                              float* __restrict__ csum) {
  int x = blockIdx.x;
  int c = x & 15, bh = x >> 4;
  int b = bh >> 6, h = bh & 63;
  int j = threadIdx.x;
  float v = dAdt[(size_t)(b * S_LEN + c * CHL + j) * NH + h].x;
  int lane = j & 63;
#pragma unroll
  for (int o = 1; o < 64; o <<= 1) {
    float u = __shfl_up(v, o);
    if (lane >= o) v += u;
  }
  __shared__ float tot;
  if (j == 63) tot = v;
  __syncthreads();
  if (j >= 64) v += tot;
  csum[(size_t)bh * S_LEN + c * CHL + j] = v;
}

// ---------------- chunk state: T_c[d,n] = sum_j w_j x_j[d] B_j[n] ------------
// grid (b,h,c)=2048 x 256 (4 waves, wave = 16-row d strip)
__global__ __launch_bounds__(256) void chunk_state_k(const unsigned short* __restrict__ xbcc,
                                                     const unsigned short* __restrict__ BT,
                                                     const float* __restrict__ csum,
                                                     const float2* __restrict__ dAdt,
                                                     unsigned short* __restrict__ states) {
  int x = blockIdx.x;
  int c = x & 15, h = (x >> 4) & 63, b = x >> 10;
  int tid = threadIdx.x, w = tid >> 6, lane = tid & 63;
  int l16 = lane & 15, kq = lane >> 4, g = h >> 3;

  __shared__ float csL[CHL], wL[CHL];
  __shared__ unsigned short tX[CHL][66];

  if (tid < CHL) csL[tid] = csum[(size_t)(b * NH + h) * S_LEN + c * CHL + tid];
#pragma unroll
  for (int k = 0; k < 8; k++) {
    int idx = tid + k * 256;
    int r = idx >> 4, c4 = (idx & 15) * 4;
    ushort4 v = *(const ushort4*)(xbcc + (size_t)(b * S_LEN + c * CHL + r) * CONVD + h * HD + c4);
    tX[r][c4] = v.x; tX[r][c4 + 1] = v.y; tX[r][c4 + 2] = v.z; tX[r][c4 + 3] = v.w;
  }
  __syncthreads();
  if (tid < CHL) {
    float dtv = dAdt[(size_t)(b * S_LEN + c * CHL + tid) * NH + h].y;
    wL[tid] = expf(csL[CHL - 1] - csL[tid]) * dtv;
  }
  __syncthreads();

  const unsigned short* bbase = BT + (size_t)b * GN * S_LEN + (size_t)(g * NST) * S_LEN + c * CHL;

  f32x4 acc[8];
#pragma unroll
  for (int nf = 0; nf < 8; nf++) acc[nf] = (f32x4){0.f, 0.f, 0.f, 0.f};

#pragma unroll
  for (int ks = 0; ks < 4; ks++) {
    bf16x8 af;
#pragma unroll
    for (int e = 0; e < 8; e++) {
      int j = ks * 32 + kq * 8 + e;
      af[e] = (short)f2b(b2f(tX[j][w * 16 + l16]) * wL[j]);
    }
#pragma unroll
    for (int nf = 0; nf < 8; nf++) {
      bf16x8 bf = *(const bf16x8*)(bbase + (size_t)(nf * 16 + l16) * S_LEN + ks * 32 + kq * 8);
      acc[nf] = __builtin_amdgcn_mfma_f32_16x16x32_bf16(af, bf, acc[nf], 0, 0, 0);
    }
  }
  unsigned short* ob = states + (size_t)((b * NH + h) * NCH + c) * (HD * NST);
#pragma unroll
  for (int nf = 0; nf < 8; nf++)
#pragma unroll
    for (int r = 0; r < 4; r++)
      ob[(w * 16 + kq * 4 + r) * NST + nf * 16 + l16] = f2b(acc[nf][r]);
}

// ---------------- state passing: P_c = prefix; in-place over states ----------
// 1M threads: (b,h,d,n); 16 sequential chunks each
__global__ __launch_bounds__(256) void state_pass_k(unsigned short* __restrict__ states,
                                                    const float* __restrict__ csum) {
  int idx = blockIdx.x * 256 + threadIdx.x;
  int n = idx & 127, d = (idx >> 7) & 63, bh = idx >> 13;
  size_t base = (size_t)bh * NCH * (HD * NST) + d * NST + n;
  size_t csb = (size_t)bh * S_LEN + (CHL - 1);
  float R = 0.f;
#pragma unroll
  for (int c = 0; c < NCH; c++) {
    float T = b2f(states[base + (size_t)c * (HD * NST)]);
    float Dc = expf(csum[csb + c * CHL]);
    states[base + (size_t)c * (HD * NST)] = f2b(R);
    R = fmaf(Dc, R, T);
  }
}

// ---------------- chunk scan: y = (mask o C B^T) X + diag(v) C P^T -----------
// grid (b,h,c)=2048 x 256 (4 waves, wave = 32-row i strip)
__global__ __launch_bounds__(256) void chunk_scan_k(const unsigned short* __restrict__ xbcc,
                                                    const unsigned short* __restrict__ states,
                                                    const float* __restrict__ csum,
                                                    const float2* __restrict__ dAdt,
                                                    unsigned short* __restrict__ yb) {
  int x = blockIdx.x;
  int c = x & 15, h = (x >> 4) & 63, b = x >> 10;
  int tid = threadIdx.x, w = tid >> 6, lane = tid & 63;
  int l16 = lane & 15, kq = lane >> 4, g = h >> 3;
  int iw = w * 32;

  __shared__ float csL[CHL], dtL[CHL];
  __shared__ unsigned short tX[CHL][66];
  __shared__ unsigned short stil[4][32][136];

  if (tid < CHL) {
    csL[tid] = csum[(size_t)(b * NH + h) * S_LEN + c * CHL + tid];
    dtL[tid] = dAdt[(size_t)(b * S_LEN + c * CHL + tid) * NH + h].y;
  }
#pragma unroll
  for (int k = 0; k < 8; k++) {
    int idx = tid + k * 256;
    int r = idx >> 4, c4 = (idx & 15) * 4;
    ushort4 v = *(const ushort4*)(xbcc + (size_t)(b * S_LEN + c * CHL + r) * CONVD + h * HD + c4);
    tX[r][c4] = v.x; tX[r][c4 + 1] = v.y; tX[r][c4 + 2] = v.z; tX[r][c4 + 3] = v.w;
  }
  __syncthreads();

  const unsigned short* Cb = xbcc + (size_t)(b * S_LEN + c * CHL) * CONVD + INTER + GN + g * NST;
  const unsigned short* Bb = xbcc + (size_t)(b * S_LEN + c * CHL) * CONVD + INTER + g * NST;

  // C fragments (kept for phase 3)
  bf16x8 cfr[2][4];
#pragma unroll
  for (int mf = 0; mf < 2; mf++)
#pragma unroll
    for (int ks = 0; ks < 4; ks++)
      cfr[mf][ks] = *(const bf16x8*)(Cb + (size_t)(iw + mf * 16 + l16) * CONVD + ks * 32 + kq * 8);

  // Phase 1: Scores = C . B^T (k = n-state)
  f32x4 acc1[2][8];
#pragma unroll
  for (int mf = 0; mf < 2; mf++)
#pragma unroll
    for (int nf = 0; nf < 8; nf++) acc1[mf][nf] = (f32x4){0.f, 0.f, 0.f, 0.f};
#pragma unroll
  for (int ks = 0; ks < 4; ks++)
#pragma unroll
    for (int nf = 0; nf < 8; nf++) {
      bf16x8 bf = *(const bf16x8*)(Bb + (size_t)(nf * 16 + l16) * CONVD + ks * 32 + kq * 8);
      acc1[0][nf] = __builtin_amdgcn_mfma_f32_16x16x32_bf16(cfr[0][ks], bf, acc1[0][nf], 0, 0, 0);
      acc1[1][nf] = __builtin_amdgcn_mfma_f32_16x16x32_bf16(cfr[1][ks], bf, acc1[1][nf], 0, 0, 0);
    }

  // mask + exp-decay weight -> S~ in LDS (wave-private strip)
#pragma unroll
  for (int mf = 0; mf < 2; mf++)
#pragma unroll
    for (int nf = 0; nf < 8; nf++)
#pragma unroll
      for (int r = 0; r < 4; r++) {
        int il = iw + mf * 16 + kq * 4 + r;
        int j = nf * 16 + l16;
        float v = (j <= il) ? acc1[mf][nf][r] * expf(csL[il] - csL[j]) * dtL[j] : 0.f;
        stil[w][mf * 16 + kq * 4 + r][j] = f2b(v);
      }

  // Phase 2: Y_intra = S~ . X  (k = j, only j-blocks <= strip)
  f32x4 acc[2][4];
#pragma unroll
  for (int mf = 0; mf < 2; mf++)
#pragma unroll
    for (int df = 0; df < 4; df++) acc[mf][df] = (f32x4){0.f, 0.f, 0.f, 0.f};
  for (int ks2 = 0; ks2 <= w; ks2++) {
    bf16x8 sa0 = *(const bf16x8*)&stil[w][l16][ks2 * 32 + kq * 8];
    bf16x8 sa1 = *(const bf16x8*)&stil[w][16 + l16][ks2 * 32 + kq * 8];
#pragma unroll
    for (int df = 0; df < 4; df++) {
      bf16x8 xf;
#pragma unroll
      for (int e = 0; e < 8; e++) xf[e] = (short)tX[ks2 * 32 + kq * 8 + e][df * 16 + l16];
      acc[0][df] = __builtin_amdgcn_mfma_f32_16x16x32_bf16(sa0, xf, acc[0][df], 0, 0, 0);
      acc[1][df] = __builtin_amdgcn_mfma_f32_16x16x32_bf16(sa1, xf, acc[1][df], 0, 0, 0);
    }
  }

  // Phase 3: Y_inter = diag(v_i) C . P^T  (k = n-state); scale C frags by v_i
#pragma unroll
  for (int mf = 0; mf < 2; mf++) {
    float vi = expf(csL[iw + mf * 16 + l16]);
#pragma unroll
    for (int ks = 0; ks < 4; ks++) {
      bf16x8 s = cfr[mf][ks], d2;
#pragma unroll
      for (int e = 0; e < 8; e++) d2[e] = (short)f2b(b2f((unsigned short)s[e]) * vi);
      cfr[mf][ks] = d2;
    }
  }
  const unsigned short* Pb = states + (size_t)((b * NH + h) * NCH + c) * (HD * NST);
#pragma unroll
  for (int ks = 0; ks < 4; ks++)
#pragma unroll
    for (int df = 0; df < 4; df++) {
      bf16x8 pf = *(const bf16x8*)(Pb + (size_t)(df * 16 + l16) * NST + ks * 32 + kq * 8);
      acc[0][df] = __builtin_amdgcn_mfma_f32_16x16x32_bf16(cfr[0][ks], pf, acc[0][df], 0, 0, 0);
      acc[1][df] = __builtin_amdgcn_mfma_f32_16x16x32_bf16(cfr[1][ks], pf, acc[1][df], 0, 0, 0);
    }

#pragma unroll
  for (int mf = 0; mf < 2; mf++)
#pragma unroll
    for (int df = 0; df < 4; df++)
#pragma unroll
      for (int r = 0; r < 4; r++)
        yb[(size_t)(b * S_LEN + c * CHL + iw + mf * 16 + kq * 4 + r) * INTER + h * HD + df * 16 + l16]
            = f2b(acc[mf][df][r]);
}

// ---------------- gated RMSNorm (+ D*x skip) -> bf16 -------------------------
__global__ __launch_bounds__(256) void gatenorm_k(const unsigned short* __restrict__ y,
                                                  const unsigned short* __restrict__ xbcc,
                                                  const unsigned short* __restrict__ gate,
                                                  const float* __restrict__ Dp,
                                                  const float* __restrict__ nw,
                                                  unsigned short* __restrict__ nrm) {
  int row = blockIdx.x, tid = threadIdx.x;
  int c0 = tid * 16;
  const unsigned short* yr = y + (size_t)row * INTER + c0;
  const unsigned short* xr = xbcc + (size_t)row * CONVD + c0;
  const unsigned short* gr = gate + (size_t)row * INTER + c0;
  float Dv = Dp[c0 >> 6];
  uint4 yv[2], xv[2], gg[2];
  yv[0] = *(const uint4*)yr; yv[1] = *(const uint4*)(yr + 8);
  xv[0] = *(const uint4*)xr; xv[1] = *(const uint4*)(xr + 8);
  gg[0] = *(const uint4*)gr; gg[1] = *(const uint4*)(gr + 8);
  float yf[16], xf[16], gf[16];
#pragma unroll
  for (int j = 0; j < 2; j++) {
    const unsigned* yu = (const unsigned*)&yv[j];
    const unsigned* xu = (const unsigned*)&xv[j];
    const unsigned* gu = (const unsigned*)&gg[j];
#pragma unroll
    for (int q = 0; q < 4; q++) {
      unpack2(yu[q], yf[j * 8 + q * 2], yf[j * 8 + q * 2 + 1]);
      unpack2(xu[q], xf[j * 8 + q * 2], xf[j * 8 + q * 2 + 1]);
      unpack2(gu[q], gf[j * 8 + q * 2], gf[j * 8 + q * 2 + 1]);
    }
  }
  float gv[16];
  float ss = 0.f;
#pragma unroll
  for (int i = 0; i < 16; i++) {
    float gt = gf[i];
    float v = (yf[i] + Dv * xf[i]) * (gt / (1.f + expf(-gt)));
    gv[i] = v;
    ss = fmaf(v, v, ss);
  }
#pragma unroll
  for (int m = 1; m < 64; m <<= 1) ss += __shfl_xor(ss, m);
  __shared__ float red[4];
  if ((tid & 63) == 0) red[tid >> 6] = ss;
  __syncthreads();
  float scale = rsqrtf((red[0] + red[1] + red[2] + red[3]) * (1.f / INTER) + 1e-5f);
  unsigned short ob[16];
#pragma unroll
  for (int i = 0; i < 16; i++) ob[i] = f2b(gv[i] * scale * nw[c0 + i]);
  unsigned short* op = nrm + (size_t)row * INTER + c0;
  *(uint4*)op = *(uint4*)ob;
  *(uint4*)(op + 8) = *(uint4*)(ob + 8);
}

extern "C" void kernel_launch(void* const* d_in, const int* in_sizes, int n_in,
                              void* d_out, int out_size, void* d_ws, size_t ws_size,
                              hipStream_t stream) {
  const float* hs   = (const float*)d_in[0];
  const float* Wz   = (const float*)d_in[1];
  const float* Wx   = (const float*)d_in[2];
  const float* WB   = (const float*)d_in[3];
  const float* WC   = (const float*)d_in[4];
  const float* Wdt  = (const float*)d_in[5];
  const float* cw   = (const float*)d_in[6];
  const float* cb   = (const float*)d_in[7];
  const float* dtb  = (const float*)d_in[8];
  const float* alog = (const float*)d_in[9];
  const float* Dp   = (const float*)d_in[10];
  const float* nw   = (const float*)d_in[11];
  const float* Wout = (const float*)d_in[12];
  float* outp = (float*)d_out;

  // Workspace: peak 222,298,112 B (< 245,366,784 known-safe).
  // Aliases (time-disjoint): states@0 over hsb/Wt1 (dead after GEMM1);
  // yb over xbcR (dead after conv); nrm@0 over states (dead after chunk_scan).
  char* ws = (char*)d_ws;
  unsigned short* hsb   = (unsigned short*)(ws);                  // 16 MiB
  unsigned short* Wt1   = (unsigned short*)(ws + 16777216ull);    // 40 MiB
  unsigned short* WoT   = (unsigned short*)(ws + 58720256ull);    // 16 MiB
  unsigned short* gateB = (unsigned short*)(ws + 75497472ull);    // 32 MiB
  unsigned short* xbcR  = (unsigned short*)(ws + 109051904ull);   // 48 MiB
  unsigned short* xbcc  = (unsigned short*)(ws + 159383552ull);   // 48 MiB
  float2*         dAdt  = (float2*)(ws + 209715200ull);           // 2 MiB
  float*          csum  = (float*)(ws + 211812352ull);            // 2 MiB
  unsigned short* BT    = (unsigned short*)(ws + 213909504ull);   // 8 MiB
  unsigned short* states= (unsigned short*)(ws);                  // 32 MiB (alias)
  unsigned short* yb    = (unsigned short*)(ws + 109051904ull);   // 32 MiB (alias)
  unsigned short* nrm   = (unsigned short*)(ws);                  // 32 MiB (alias)

  cast_k<<<(ROWS * HID / 4) / 256, 256, 0, stream>>>(hs, hsb);
  tcast_k<<<dim3(INTER / 64, HID / 64), 256, 0, stream>>>(Wz, Wt1, HID, INTER);
  tcast_k<<<dim3(INTER / 64, HID / 64), 256, 0, stream>>>(Wx, Wt1 + (size_t)INTER * HID, HID, INTER);
  tcast_k<<<dim3(GN / 64, HID / 64), 256, 0, stream>>>(WB, Wt1 + (size_t)2 * INTER * HID, HID, GN);
  tcast_k<<<dim3(GN / 64, HID / 64), 256, 0, stream>>>(WC, Wt1 + (size_t)(2 * INTER + GN) * HID, HID, GN);
  tcast_k<<<dim3(HID / 64, INTER / 64), 256, 0, stream>>>(Wout, WoT, INTER, HID);

  gemm_split<<<dim3(NPROJ / 128, ROWS / 128), 256, 0, stream>>>(hsb, Wt1, gateB, xbcR, ROWS, NPROJ, HID);
  dt_kernel<<<ROWS / 16, 256, 0, stream>>>(hs, Wdt, dtb, alog, dAdt);
  conv_silu_k<<<(ROWS * (CONVD / 4)) / 256, 256, 0, stream>>>(xbcR, cw, cb, xbcc);

  transB_k<<<dim3(GN / 64, S_LEN / 64, NBATCH), 256, 0, stream>>>(xbcc, BT);
  csum_k<<<NBATCH * NH * NCH, 128, 0, stream>>>(dAdt, csum);
  chunk_state_k<<<NBATCH * NH * NCH, 256, 0, stream>>>(xbcc, BT, csum, dAdt, states);
  state_pass_k<<<(NBATCH * NH * HD * NST) / 256, 256, 0, stream>>>(states, csum);
  chunk_scan_k<<<NBATCH * NH * NCH, 256, 0, stream>>>(xbcc, states, csum, dAdt, yb);

  gatenorm_k<<<ROWS, 256, 0, stream>>>(yb, xbcc, gateB, Dp, nw, nrm);
  gemm_bt<float><<<dim3(HID / 128, ROWS / 128), 256, 0, stream>>>(nrm, WoT, outp, ROWS, HID, INTER);
}